// Round 2
// baseline (1755.168 us; speedup 1.0000x reference)
//
#include <hip/hip_runtime.h>

// Swin window attention, fused per-window kernel, round 2.
// Changes vs round 1:
//  - No LDS weight staging: B-fragments loaded straight from L2-resident bf16
//    weights into registers -> phases 1/3 have no barriers (3 barriers/block total).
//  - Wave partition 2 M-groups x 4 N-slices: each B-frag feeds 2 MFMAs.
//  - T2 XOR swizzle on q/O and K LDS tiles; V stored transposed+swizzled so the
//    PV B-operand is a single ds_read_b128.
//  - Scale folded into q at the phase-1 C-write.

#define NTOK 49
#define DIM 384
#define HEADS 12
#define QKV_ELEMS (1152*384)
#define PROJ_ELEMS (384*384)
#define BIAS_ELEMS (HEADS*NTOK*NTOK)
#define PSTR 56
#define SCALE 0.17677669529663687f

typedef __attribute__((ext_vector_type(8))) __bf16 bf16x8;
typedef __attribute__((ext_vector_type(4))) float f32x4;

union BF8 { bf16x8 v; unsigned short u[8]; };

__device__ __forceinline__ unsigned short f2bf(float f) {
  union { float f; unsigned u; } x; x.f = f;
  unsigned r = x.u + 0x7fffu + ((x.u >> 16) & 1u);   // RNE
  return (unsigned short)(r >> 16);
}

__device__ __forceinline__ bf16x8 zbf8() {
  BF8 z;
  #pragma unroll
  for (int j = 0; j < 8; ++j) z.u[j] = 0;
  return z.v;
}

__global__ void prep_kernel(const float* __restrict__ qkv_w,
                            const float* __restrict__ proj_w,
                            const float* __restrict__ bias_table,
                            const int* __restrict__ rel_idx,
                            unsigned short* __restrict__ wq,
                            unsigned short* __restrict__ wp,
                            float* __restrict__ bias_full) {
  int i = blockIdx.x * 256 + threadIdx.x;
  if (i < QKV_ELEMS) {
    wq[i] = f2bf(qkv_w[i]);
  } else if (i < QKV_ELEMS + PROJ_ELEMS) {
    int j = i - QKV_ELEMS;
    wp[j] = f2bf(proj_w[j]);
  } else if (i < QKV_ELEMS + PROJ_ELEMS + BIAS_ELEMS) {
    int j = i - QKV_ELEMS - PROJ_ELEMS;
    int h = j / (NTOK * NTOK), rc = j % (NTOK * NTOK);
    bias_full[j] = bias_table[rel_idx[rc] * HEADS + h];
  }
}

// LDS element offsets (u16 units)
#define OFF_Q 0
#define OFF_K (49*384)             // 18816
#define OFF_V (2*49*384)           // 37632
#define OFF_P (OFF_V + 384*64)     // 62208
#define LDS_ELEMS (OFF_P + 8*16*PSTR)   // 69376
#define LDS_BYTES (LDS_ELEMS*2)         // 138752 B

// q/O and K tiles: row-major [49][384], XOR-swizzle elem-col bits 3..5 by row&7
__device__ __forceinline__ int swzq(int row, int colE) {
  return row * 384 + (colE ^ ((row & 7) << 3));
}
// V transposed: [384 ch][64 tok], XOR-swizzle tok bits 3..5 by ch&7
__device__ __forceinline__ int swzv(int ch, int tokE) {
  return ch * 64 + (tokE ^ ((ch & 7) << 3));
}

__global__ __launch_bounds__(512, 2) void fused_win_attn(
    const float* __restrict__ x, const float* __restrict__ mask,
    const float* __restrict__ qkv_b, const float* __restrict__ proj_b,
    const unsigned short* __restrict__ wq, const unsigned short* __restrict__ wp,
    const float* __restrict__ bias_full, float* __restrict__ out) {
  extern __shared__ unsigned short lds[];
  unsigned short* qO = lds + OFF_Q;   // q, later O
  unsigned short* kB = lds + OFF_K;
  unsigned short* vT = lds + OFF_V;   // transposed V [384][64]
  unsigned short* PB = lds + OFF_P;   // 8 x [16][56]

  const int tid  = threadIdx.x;
  const int wave = tid >> 6, lane = tid & 63;
  const int g = lane >> 4, li = lane & 15;
  const int win = blockIdx.x, wi = win & 63;
  const int mgrp = wave >> 2, ng = wave & 3;   // 2 M-groups x 4 N-slices

  // zero vT (pad tokens must be 0, not NaN garbage, for the PV MFMA)
  {
    uint4 z4 = {0u, 0u, 0u, 0u};
    uint4* p = (uint4*)(lds + OFF_V);
    #pragma unroll
    for (int i = 0; i < 6; ++i) p[tid + i * 512] = z4;
  }

  // ---- phase 0: load A-fragments for this wave's 2 M-tiles (fp32 -> bf16) ----
  bf16x8 afr[2][12];
  #pragma unroll
  for (int m2 = 0; m2 < 2; ++m2) {
    int row = (mgrp * 2 + m2) * 16 + li;
    if (row < NTOK) {
      const float* xr = x + ((long)win * NTOK + row) * DIM + g * 8;
      #pragma unroll
      for (int ks = 0; ks < 12; ++ks) {
        float4 f0 = *(const float4*)(xr + ks * 32);
        float4 f1 = *(const float4*)(xr + ks * 32 + 4);
        BF8 t;
        t.u[0] = f2bf(f0.x); t.u[1] = f2bf(f0.y); t.u[2] = f2bf(f0.z); t.u[3] = f2bf(f0.w);
        t.u[4] = f2bf(f1.x); t.u[5] = f2bf(f1.y); t.u[6] = f2bf(f1.z); t.u[7] = f2bf(f1.w);
        afr[m2][ks] = t.v;
      }
    } else {
      bf16x8 z = zbf8();
      #pragma unroll
      for (int ks = 0; ks < 12; ++ks) afr[m2][ks] = z;
    }
  }
  __syncthreads();   // vT zeros visible before phase-1 v-writes land

  // ---- phase 1: QKV GEMM, no barriers. B-frags straight from L2. ----
  for (int c = 0; c < 9; ++c) {
    f32x4 acc[2][2];
    #pragma unroll
    for (int m2 = 0; m2 < 2; ++m2)
      #pragma unroll
      for (int nt = 0; nt < 2; ++nt) acc[m2][nt] = (f32x4){0.f, 0.f, 0.f, 0.f};

    const unsigned short* bp0 = wq + (c * 128 + ng * 32 + li) * DIM + g * 8;
    const unsigned short* bp1 = bp0 + 16 * DIM;
    #pragma unroll
    for (int kst = 0; kst < 6; ++kst) {
      #pragma unroll
      for (int k2 = 0; k2 < 2; ++k2) {
        int ko = kst * 64 + k2 * 32;
        bf16x8 b0 = *(const bf16x8*)(bp0 + ko);
        bf16x8 b1 = *(const bf16x8*)(bp1 + ko);
        int ai = kst * 2 + k2;
        acc[0][0] = __builtin_amdgcn_mfma_f32_16x16x32_bf16(afr[0][ai], b0, acc[0][0], 0, 0, 0);
        acc[1][0] = __builtin_amdgcn_mfma_f32_16x16x32_bf16(afr[1][ai], b0, acc[1][0], 0, 0, 0);
        acc[0][1] = __builtin_amdgcn_mfma_f32_16x16x32_bf16(afr[0][ai], b1, acc[0][1], 0, 0, 0);
        acc[1][1] = __builtin_amdgcn_mfma_f32_16x16x32_bf16(afr[1][ai], b1, acc[1][1], 0, 0, 0);
      }
    }

    // C-write to LDS (+bias; q gets the softmax scale folded in)
    #pragma unroll
    for (int nt = 0; nt < 2; ++nt) {
      int colg = c * 128 + ng * 32 + nt * 16 + li;
      float qb = qkv_b[colg];
      int cc = colg - (c / 3) * DIM;
      #pragma unroll
      for (int m2 = 0; m2 < 2; ++m2) {
        #pragma unroll
        for (int r4 = 0; r4 < 4; ++r4) {
          int row = (mgrp * 2 + m2) * 16 + g * 4 + r4;
          if (row < NTOK) {
            float val = acc[m2][nt][r4] + qb;
            if (c < 3)      qO[swzq(row, cc)] = f2bf(val * SCALE);
            else if (c < 6) kB[swzq(row, cc)] = f2bf(val);
            else            vT[swzv(cc, row)] = f2bf(val);
          }
        }
      }
    }
  }
  __syncthreads();

  // ---- phase 2: attention, 48 tasks (h, mtile), 6 per wave, no barriers ----
  for (int t6 = 0; t6 < 6; ++t6) {
    const int task = wave + t6 * 8;
    const int h = task >> 2, amt = task & 3;

    bf16x8 qa;
    {
      int row = amt * 16 + li;
      qa = (row < NTOK) ? *(const bf16x8*)&qO[swzq(row, h * 32 + g * 8)] : zbf8();
    }
    f32x4 sa[4];
    #pragma unroll
    for (int nt = 0; nt < 4; ++nt) {
      int tok = nt * 16 + li;
      bf16x8 kb = (tok < NTOK) ? *(const bf16x8*)&kB[swzq(tok, h * 32 + g * 8)] : zbf8();
      f32x4 z4 = (f32x4){0.f, 0.f, 0.f, 0.f};
      sa[nt] = __builtin_amdgcn_mfma_f32_16x16x32_bf16(qa, kb, z4, 0, 0, 0);
    }

    // + bias + mask (scale already folded into q); pad cols -> -1e30
    float sv[4][4];
    #pragma unroll
    for (int nt = 0; nt < 4; ++nt) {
      int col = nt * 16 + li;
      #pragma unroll
      for (int r4 = 0; r4 < 4; ++r4) {
        int row = amt * 16 + g * 4 + r4;
        float val;
        if (col < NTOK) {
          val = sa[nt][r4];
          if (row < NTOK)
            val += bias_full[h * (NTOK * NTOK) + row * NTOK + col]
                 + mask[wi * (NTOK * NTOK) + row * NTOK + col];
        } else {
          val = -1e30f;
        }
        sv[nt][r4] = val;
      }
    }

    // wave-parallel softmax over each row (one 16-lane group per row)
    #pragma unroll
    for (int r4 = 0; r4 < 4; ++r4) {
      float m = fmaxf(fmaxf(sv[0][r4], sv[1][r4]), fmaxf(sv[2][r4], sv[3][r4]));
      m = fmaxf(m, __shfl_xor(m, 1));
      m = fmaxf(m, __shfl_xor(m, 2));
      m = fmaxf(m, __shfl_xor(m, 4));
      m = fmaxf(m, __shfl_xor(m, 8));
      float s = 0.f;
      #pragma unroll
      for (int nt = 0; nt < 4; ++nt) {
        float e = __expf(sv[nt][r4] - m);
        sv[nt][r4] = e;
        s += e;
      }
      s += __shfl_xor(s, 1); s += __shfl_xor(s, 2);
      s += __shfl_xor(s, 4); s += __shfl_xor(s, 8);
      float inv = 1.f / s;
      #pragma unroll
      for (int nt = 0; nt < 4; ++nt) sv[nt][r4] *= inv;
    }

    // P -> per-wave LDS tile [16][56] (cols 49..55 exact zeros)
    unsigned short* Pw = PB + wave * (16 * PSTR);
    #pragma unroll
    for (int nt = 0; nt < 4; ++nt) {
      int col = nt * 16 + li;
      if (col < PSTR) {
        #pragma unroll
        for (int r4 = 0; r4 < 4; ++r4) Pw[(g * 4 + r4) * PSTR + col] = f2bf(sv[nt][r4]);
      }
    }

    // O = P V via transposed V (single b128 per B-frag; pad toks are zero)
    f32x4 oa[2];
    oa[0] = (f32x4){0.f, 0.f, 0.f, 0.f};
    oa[1] = (f32x4){0.f, 0.f, 0.f, 0.f};
    #pragma unroll
    for (int k2 = 0; k2 < 2; ++k2) {
      bf16x8 pa;
      if (k2 == 1 && g == 3) pa = zbf8();
      else pa = *(const bf16x8*)&Pw[li * PSTR + k2 * 32 + g * 8];
      #pragma unroll
      for (int nt2 = 0; nt2 < 2; ++nt2) {
        int ch = h * 32 + nt2 * 16 + li;
        bf16x8 vb = *(const bf16x8*)&vT[swzv(ch, k2 * 32 + g * 8)];
        oa[nt2] = __builtin_amdgcn_mfma_f32_16x16x32_bf16(pa, vb, oa[nt2], 0, 0, 0);
      }
    }

    // O overwrites the dead q tile of this (h, amt) task
    #pragma unroll
    for (int nt2 = 0; nt2 < 2; ++nt2) {
      int col = h * 32 + nt2 * 16 + li;
      #pragma unroll
      for (int r4 = 0; r4 < 4; ++r4) {
        int row = amt * 16 + g * 4 + r4;
        if (row < NTOK) qO[swzq(row, col)] = f2bf(oa[nt2][r4]);
      }
    }
  }
  __syncthreads();

  // ---- phase 3: proj GEMM, no barriers ----
  bf16x8 ofr[2][12];
  #pragma unroll
  for (int m2 = 0; m2 < 2; ++m2) {
    int row = (mgrp * 2 + m2) * 16 + li;
    if (row < NTOK) {
      #pragma unroll
      for (int ks = 0; ks < 12; ++ks)
        ofr[m2][ks] = *(const bf16x8*)&qO[swzq(row, ks * 32 + g * 8)];
    } else {
      bf16x8 z = zbf8();
      #pragma unroll
      for (int ks = 0; ks < 12; ++ks) ofr[m2][ks] = z;
    }
  }
  for (int pc = 0; pc < 3; ++pc) {
    f32x4 acc[2][2];
    #pragma unroll
    for (int m2 = 0; m2 < 2; ++m2)
      #pragma unroll
      for (int nt = 0; nt < 2; ++nt) acc[m2][nt] = (f32x4){0.f, 0.f, 0.f, 0.f};

    const unsigned short* bp0 = wp + (pc * 128 + ng * 32 + li) * DIM + g * 8;
    const unsigned short* bp1 = bp0 + 16 * DIM;
    #pragma unroll
    for (int kst = 0; kst < 6; ++kst) {
      #pragma unroll
      for (int k2 = 0; k2 < 2; ++k2) {
        int ko = kst * 64 + k2 * 32;
        bf16x8 b0 = *(const bf16x8*)(bp0 + ko);
        bf16x8 b1 = *(const bf16x8*)(bp1 + ko);
        int ai = kst * 2 + k2;
        acc[0][0] = __builtin_amdgcn_mfma_f32_16x16x32_bf16(ofr[0][ai], b0, acc[0][0], 0, 0, 0);
        acc[1][0] = __builtin_amdgcn_mfma_f32_16x16x32_bf16(ofr[1][ai], b0, acc[1][0], 0, 0, 0);
        acc[0][1] = __builtin_amdgcn_mfma_f32_16x16x32_bf16(ofr[0][ai], b1, acc[0][1], 0, 0, 0);
        acc[1][1] = __builtin_amdgcn_mfma_f32_16x16x32_bf16(ofr[1][ai], b1, acc[1][1], 0, 0, 0);
      }
    }
    #pragma unroll
    for (int nt = 0; nt < 2; ++nt) {
      int col = pc * 128 + ng * 32 + nt * 16 + li;
      float pb = proj_b[col];
      #pragma unroll
      for (int m2 = 0; m2 < 2; ++m2) {
        #pragma unroll
        for (int r4 = 0; r4 < 4; ++r4) {
          int row = (mgrp * 2 + m2) * 16 + g * 4 + r4;
          if (row < NTOK)
            out[((long)win * NTOK + row) * DIM + col] = acc[m2][nt][r4] + pb;
        }
      }
    }
  }
}

extern "C" void kernel_launch(void* const* d_in, const int* in_sizes, int n_in,
                              void* d_out, int out_size, void* d_ws, size_t ws_size,
                              hipStream_t stream) {
  (void)in_sizes; (void)n_in; (void)out_size; (void)ws_size;
  const float* x          = (const float*)d_in[0];
  const float* mask       = (const float*)d_in[1];
  const float* qkv_w      = (const float*)d_in[2];
  const float* qkv_b      = (const float*)d_in[3];
  const float* proj_w     = (const float*)d_in[4];
  const float* proj_b     = (const float*)d_in[5];
  const float* bias_table = (const float*)d_in[6];
  const int*   rel_idx    = (const int*)d_in[7];
  float* out = (float*)d_out;

  unsigned short* wq = (unsigned short*)d_ws;
  unsigned short* wp = wq + QKV_ELEMS;
  float* bias_full = (float*)((char*)d_ws + (size_t)(QKV_ELEMS + PROJ_ELEMS) * 2);

  const int prep_total = QKV_ELEMS + PROJ_ELEMS + BIAS_ELEMS;
  prep_kernel<<<(prep_total + 255) / 256, 256, 0, stream>>>(
      qkv_w, proj_w, bias_table, rel_idx, wq, wp, bias_full);
  fused_win_attn<<<4096, 512, LDS_BYTES, stream>>>(
      x, mask, qkv_b, proj_b, wq, wp, bias_full, out);
}